// Round 1
// baseline (4038.538 us; speedup 1.0000x reference)
//
#include <hip/hip_runtime.h>
#include <cmath>

#define HD 128
#define HP 132   // padded sH row (breaks bank conflicts on column reads)
#define BM 64    // edges / nodes per block

__device__ __forceinline__ float siluf(float x) { return x / (1.0f + expf(-x)); }
__device__ __forceinline__ float sigmf(float x) { return 1.0f / (1.0f + expf(-x)); }

// Stage a [32 x 128] chunk of a row-major weight matrix W[j][k] (stride = K)
// transposed into sB[kk][j]. 256 threads: each loads 16 consecutive k of one row.
__device__ __forceinline__ void stage_w32(const float* __restrict__ W, int stride, int kb,
                                          float sB[32][HD], int tid)
{
  const int jw  = tid >> 1;
  const int kk0 = (tid & 1) * 16;
  const float* p = W + (size_t)jw * stride + kb + kk0;
#pragma unroll
  for (int u = 0; u < 16; u += 2) {
    float2 w = *(const float2*)(p + u);   // 8B-aligned (stride, kb, kk0, u all even)
    sB[kk0 + u][jw]     = w.x;
    sB[kk0 + u + 1][jw] = w.y;
  }
}

// ---------------------------------------------------------------------------
// Fused edge pipeline: gather -> 258->128 silu -> 128->128 silu -> gate -> scatter
// MODE 0: GCL edge model (attention gate, scatter mij*att into agg[N,128])
// MODE 1: Equivariant edge model (scalar s, scatter coord_diff*s into xagg[N,3])
// ---------------------------------------------------------------------------
template <int MODE>
__global__ __launch_bounds__(256, 2)
void edge_kernel(const float* __restrict__ h,
                 const float* __restrict__ radial,
                 const float* __restrict__ eattr,
                 const int* __restrict__ eidx, int E,
                 const float* __restrict__ W1, const float* __restrict__ b1,
                 const float* __restrict__ W2, const float* __restrict__ b2,
                 const float* __restrict__ awv,  // MODE0: aw[128], MODE1: w3[128]
                 const float* __restrict__ abv,  // MODE0: ab[1],  MODE1: unused
                 const float* __restrict__ cd,   // MODE1: coord_diff[E,3]
                 float* __restrict__ outbuf)     // MODE0: agg[N,128], MODE1: xagg[N,3]
{
  __shared__ float sA[32][BM];       // A chunk, transposed: sA[kk][edge]
  __shared__ float sB[32][HD];       // W chunk, transposed: sB[kk][j]
  __shared__ float sH[BM][HP];       // silu(H1) tile
  __shared__ int   sRow[BM];
  __shared__ int   sCol[BM];
  __shared__ float sRad[BM];
  __shared__ float sEa[BM];

  const int tid = threadIdx.x;
  const int e0  = blockIdx.x * BM;

  if (tid < BM) {
    int e = e0 + tid;
    if (e >= E) e = E - 1;             // clamp (loads only; stores are guarded)
    sRow[tid] = eidx[e];
    sCol[tid] = eidx[E + e];
    sRad[tid] = radial[e];
    sEa[tid]  = eattr[e];
  }
  __syncthreads();

  const int tj = tid & 15;             // output group: j = 4*tj..4*tj+3 and +64
  const int te = tid >> 4;             // edge group: edges te*4..te*4+3
  const int ja = tj * 4;
  const int jb = 64 + tj * 4;
  const int eb = te * 4;
  const int le = tid >> 2;             // staging: edge index
  const int q  = tid & 3;              // staging: 8-float slice within 32-k chunk

  float acc[4][8];
#pragma unroll
  for (int i = 0; i < 4; ++i)
#pragma unroll
    for (int u = 0; u < 8; ++u) acc[i][u] = 0.0f;

  // ---- GEMM1: e_in[64 x 258] @ W1^T, k=0..255 in 8 chunks of 32 ----
#pragma unroll 1
  for (int c = 0; c < 8; ++c) {
    const int src = (c < 4) ? sRow[le] : sCol[le];
    const int kb  = (c & 3) * 32;
    const float* hp = h + (size_t)src * HD + kb + q * 8;
    float4 v0 = *(const float4*)(hp);
    float4 v1 = *(const float4*)(hp + 4);
    const int r0 = q * 8;
    sA[r0 + 0][le] = v0.x; sA[r0 + 1][le] = v0.y;
    sA[r0 + 2][le] = v0.z; sA[r0 + 3][le] = v0.w;
    sA[r0 + 4][le] = v1.x; sA[r0 + 5][le] = v1.y;
    sA[r0 + 6][le] = v1.z; sA[r0 + 7][le] = v1.w;
    stage_w32(W1, 2 * HD + 2, c * 32, sB, tid);
    __syncthreads();
#pragma unroll
    for (int kk = 0; kk < 32; ++kk) {
      const float4 a4 = *(const float4*)&sA[kk][eb];
      const float4 bA = *(const float4*)&sB[kk][ja];
      const float4 bB = *(const float4*)&sB[kk][jb];
      const float av[4] = {a4.x, a4.y, a4.z, a4.w};
#pragma unroll
      for (int i = 0; i < 4; ++i) {
        acc[i][0] += av[i] * bA.x; acc[i][1] += av[i] * bA.y;
        acc[i][2] += av[i] * bA.z; acc[i][3] += av[i] * bA.w;
        acc[i][4] += av[i] * bB.x; acc[i][5] += av[i] * bB.y;
        acc[i][6] += av[i] * bB.z; acc[i][7] += av[i] * bB.w;
      }
    }
    __syncthreads();
  }

  // epilogue 1: tail columns (radial, edge_attr) + bias, silu, stash in sH
  {
    float wra[4], wea[4], bba[4], wrb[4], web[4], bbb[4];
#pragma unroll
    for (int u = 0; u < 4; ++u) {
      const int j1 = ja + u, j2 = jb + u;
      wra[u] = W1[(size_t)j1 * (2 * HD + 2) + 256];
      wea[u] = W1[(size_t)j1 * (2 * HD + 2) + 257];
      bba[u] = b1[j1];
      wrb[u] = W1[(size_t)j2 * (2 * HD + 2) + 256];
      web[u] = W1[(size_t)j2 * (2 * HD + 2) + 257];
      bbb[u] = b1[j2];
    }
#pragma unroll
    for (int i = 0; i < 4; ++i) {
      const float rr = sRad[eb + i];
      const float ee = sEa[eb + i];
#pragma unroll
      for (int u = 0; u < 4; ++u) {
        sH[eb + i][ja + u] = siluf(acc[i][u]     + rr * wra[u] + ee * wea[u] + bba[u]);
        sH[eb + i][jb + u] = siluf(acc[i][4 + u] + rr * wrb[u] + ee * web[u] + bbb[u]);
      }
    }
  }

  // ---- GEMM2: sH[64 x 128] @ W2^T, 4 chunks of 32 ----
  float acc2[4][8];
#pragma unroll
  for (int i = 0; i < 4; ++i)
#pragma unroll
    for (int u = 0; u < 8; ++u) acc2[i][u] = 0.0f;

#pragma unroll 1
  for (int c = 0; c < 4; ++c) {
    stage_w32(W2, HD, c * 32, sB, tid);
    __syncthreads();
#pragma unroll
    for (int k4 = 0; k4 < 8; ++k4) {
      const int k = c * 32 + k4 * 4;
      float4 a0 = *(const float4*)&sH[eb + 0][k];
      float4 a1 = *(const float4*)&sH[eb + 1][k];
      float4 a2 = *(const float4*)&sH[eb + 2][k];
      float4 a3 = *(const float4*)&sH[eb + 3][k];
      const float av[4][4] = {{a0.x, a0.y, a0.z, a0.w},
                              {a1.x, a1.y, a1.z, a1.w},
                              {a2.x, a2.y, a2.z, a2.w},
                              {a3.x, a3.y, a3.z, a3.w}};
#pragma unroll
      for (int v = 0; v < 4; ++v) {
        const float4 bA = *(const float4*)&sB[k4 * 4 + v][ja];
        const float4 bB = *(const float4*)&sB[k4 * 4 + v][jb];
#pragma unroll
        for (int i = 0; i < 4; ++i) {
          acc2[i][0] += av[i][v] * bA.x; acc2[i][1] += av[i][v] * bA.y;
          acc2[i][2] += av[i][v] * bA.z; acc2[i][3] += av[i][v] * bA.w;
          acc2[i][4] += av[i][v] * bB.x; acc2[i][5] += av[i][v] * bB.y;
          acc2[i][6] += av[i][v] * bB.z; acc2[i][7] += av[i][v] * bB.w;
        }
      }
    }
    __syncthreads();
  }

  // ---- epilogue 2 ----
  float b2a[4], b2b[4], wva[4], wvb[4];
#pragma unroll
  for (int u = 0; u < 4; ++u) {
    b2a[u] = b2[ja + u]; b2b[u] = b2[jb + u];
    wva[u] = awv[ja + u]; wvb[u] = awv[jb + u];
  }

  if constexpr (MODE == 0) {
    float mij[4][8];
    float ap[4];
#pragma unroll
    for (int i = 0; i < 4; ++i) {
      float p = 0.0f;
#pragma unroll
      for (int u = 0; u < 4; ++u) {
        float m1 = siluf(acc2[i][u] + b2a[u]);
        float m2 = siluf(acc2[i][4 + u] + b2b[u]);
        mij[i][u] = m1; mij[i][4 + u] = m2;
        p += m1 * wva[u] + m2 * wvb[u];
      }
      ap[i] = p;
    }
#pragma unroll
    for (int msk = 1; msk < 16; msk <<= 1) {
#pragma unroll
      for (int i = 0; i < 4; ++i) ap[i] += __shfl_xor(ap[i], msk, 64);
    }
    const float ab0 = abv[0];
#pragma unroll
    for (int i = 0; i < 4; ++i) {
      if (e0 + eb + i < E) {
        const float at = sigmf(ap[i] + ab0);
        float* dst = outbuf + (size_t)sRow[eb + i] * HD;
#pragma unroll
        for (int u = 0; u < 4; ++u) {
          unsafeAtomicAdd(dst + ja + u, mij[i][u] * at);
          unsafeAtomicAdd(dst + jb + u, mij[i][4 + u] * at);
        }
      }
    }
  } else {
    float ap[4];
#pragma unroll
    for (int i = 0; i < 4; ++i) {
      float p = 0.0f;
#pragma unroll
      for (int u = 0; u < 4; ++u) {
        p += siluf(acc2[i][u] + b2a[u]) * wva[u];
        p += siluf(acc2[i][4 + u] + b2b[u]) * wvb[u];
      }
      ap[i] = p;
    }
#pragma unroll
    for (int msk = 1; msk < 16; msk <<= 1) {
#pragma unroll
      for (int i = 0; i < 4; ++i) ap[i] += __shfl_xor(ap[i], msk, 64);
    }
    if (tj == 0) {
#pragma unroll
      for (int i = 0; i < 4; ++i) {
        const int e = e0 + eb + i;
        if (e < E) {
          const float s = ap[i];
          float* dst = outbuf + (size_t)sRow[eb + i] * 3;
          unsafeAtomicAdd(dst + 0, cd[(size_t)e * 3 + 0] * s);
          unsafeAtomicAdd(dst + 1, cd[(size_t)e * 3 + 1] * s);
          unsafeAtomicAdd(dst + 2, cd[(size_t)e * 3 + 2] * s);
        }
      }
    }
  }
}

// ---------------------------------------------------------------------------
// Node model: msg = silu([h, agg/100] @ nw1^T + nb1) @ nw2^T + nb2; h += msg
// Each block owns 64 nodes; in-place h update (exclusive row ownership).
// ---------------------------------------------------------------------------
__global__ __launch_bounds__(256, 2)
void node_kernel(float* __restrict__ h, const float* __restrict__ agg, int N,
                 const float* __restrict__ W1, const float* __restrict__ b1,
                 const float* __restrict__ W2, const float* __restrict__ b2)
{
  __shared__ float sA[32][BM];
  __shared__ float sB[32][HD];
  __shared__ float sH[BM][HP];

  const int tid = threadIdx.x;
  const int n0  = blockIdx.x * BM;

  const int tj = tid & 15;
  const int te = tid >> 4;
  const int ja = tj * 4;
  const int jb = 64 + tj * 4;
  const int eb = te * 4;
  const int le = tid >> 2;
  const int q  = tid & 3;

  float acc[4][8];
#pragma unroll
  for (int i = 0; i < 4; ++i)
#pragma unroll
    for (int u = 0; u < 8; ++u) acc[i][u] = 0.0f;

#pragma unroll 1
  for (int c = 0; c < 8; ++c) {
    int n = n0 + le;
    if (n >= N) n = N - 1;
    const int kb = (c & 3) * 32;
    const float* srcp = (c < 4) ? (h + (size_t)n * HD + kb + q * 8)
                                : (agg + (size_t)n * HD + kb + q * 8);
    const float sc = (c < 4) ? 1.0f : 0.01f;   // agg / normalization_factor
    float4 v0 = *(const float4*)(srcp);
    float4 v1 = *(const float4*)(srcp + 4);
    const int r0 = q * 8;
    sA[r0 + 0][le] = v0.x * sc; sA[r0 + 1][le] = v0.y * sc;
    sA[r0 + 2][le] = v0.z * sc; sA[r0 + 3][le] = v0.w * sc;
    sA[r0 + 4][le] = v1.x * sc; sA[r0 + 5][le] = v1.y * sc;
    sA[r0 + 6][le] = v1.z * sc; sA[r0 + 7][le] = v1.w * sc;
    stage_w32(W1, 2 * HD, c * 32, sB, tid);
    __syncthreads();
#pragma unroll
    for (int kk = 0; kk < 32; ++kk) {
      const float4 a4 = *(const float4*)&sA[kk][eb];
      const float4 bA = *(const float4*)&sB[kk][ja];
      const float4 bB = *(const float4*)&sB[kk][jb];
      const float av[4] = {a4.x, a4.y, a4.z, a4.w};
#pragma unroll
      for (int i = 0; i < 4; ++i) {
        acc[i][0] += av[i] * bA.x; acc[i][1] += av[i] * bA.y;
        acc[i][2] += av[i] * bA.z; acc[i][3] += av[i] * bA.w;
        acc[i][4] += av[i] * bB.x; acc[i][5] += av[i] * bB.y;
        acc[i][6] += av[i] * bB.z; acc[i][7] += av[i] * bB.w;
      }
    }
    __syncthreads();
  }

  {
    float bba[4], bbb[4];
#pragma unroll
    for (int u = 0; u < 4; ++u) { bba[u] = b1[ja + u]; bbb[u] = b1[jb + u]; }
#pragma unroll
    for (int i = 0; i < 4; ++i) {
#pragma unroll
      for (int u = 0; u < 4; ++u) {
        sH[eb + i][ja + u] = siluf(acc[i][u] + bba[u]);
        sH[eb + i][jb + u] = siluf(acc[i][4 + u] + bbb[u]);
      }
    }
  }

  float acc2[4][8];
#pragma unroll
  for (int i = 0; i < 4; ++i)
#pragma unroll
    for (int u = 0; u < 8; ++u) acc2[i][u] = 0.0f;

#pragma unroll 1
  for (int c = 0; c < 4; ++c) {
    stage_w32(W2, HD, c * 32, sB, tid);
    __syncthreads();
#pragma unroll
    for (int k4 = 0; k4 < 8; ++k4) {
      const int k = c * 32 + k4 * 4;
      float4 a0 = *(const float4*)&sH[eb + 0][k];
      float4 a1 = *(const float4*)&sH[eb + 1][k];
      float4 a2 = *(const float4*)&sH[eb + 2][k];
      float4 a3 = *(const float4*)&sH[eb + 3][k];
      const float av[4][4] = {{a0.x, a0.y, a0.z, a0.w},
                              {a1.x, a1.y, a1.z, a1.w},
                              {a2.x, a2.y, a2.z, a2.w},
                              {a3.x, a3.y, a3.z, a3.w}};
#pragma unroll
      for (int v = 0; v < 4; ++v) {
        const float4 bA = *(const float4*)&sB[k4 * 4 + v][ja];
        const float4 bB = *(const float4*)&sB[k4 * 4 + v][jb];
#pragma unroll
        for (int i = 0; i < 4; ++i) {
          acc2[i][0] += av[i][v] * bA.x; acc2[i][1] += av[i][v] * bA.y;
          acc2[i][2] += av[i][v] * bA.z; acc2[i][3] += av[i][v] * bA.w;
          acc2[i][4] += av[i][v] * bB.x; acc2[i][5] += av[i][v] * bB.y;
          acc2[i][6] += av[i][v] * bB.z; acc2[i][7] += av[i][v] * bB.w;
        }
      }
    }
    __syncthreads();
  }

  float b2a[4], b2b[4];
#pragma unroll
  for (int u = 0; u < 4; ++u) { b2a[u] = b2[ja + u]; b2b[u] = b2[jb + u]; }
#pragma unroll
  for (int i = 0; i < 4; ++i) {
    const int n = n0 + eb + i;
    if (n < N) {
      float* hp = h + (size_t)n * HD;
#pragma unroll
      for (int u = 0; u < 4; ++u) {
        hp[ja + u] += acc2[i][u] + b2a[u];        // residual: h = h + msg
        hp[jb + u] += acc2[i][4 + u] + b2b[u];
      }
    }
  }
}

// radial + coord_diff precompute
__global__ void coord2diff_kernel(const float* __restrict__ x,
                                  const int* __restrict__ eidx, int E,
                                  float* __restrict__ radial, float* __restrict__ cd)
{
  const int e = blockIdx.x * 256 + threadIdx.x;
  if (e >= E) return;
  const int r = eidx[e], c = eidx[E + e];
  const float dx = x[(size_t)r * 3 + 0] - x[(size_t)c * 3 + 0];
  const float dy = x[(size_t)r * 3 + 1] - x[(size_t)c * 3 + 1];
  const float dz = x[(size_t)r * 3 + 2] - x[(size_t)c * 3 + 2];
  const float rad = dx * dx + dy * dy + dz * dz;
  radial[e] = rad;
  const float inv = 1.0f / (sqrtf(rad + 1e-8f) + 1.0f);   // NORM_CONSTANT = 1
  cd[(size_t)e * 3 + 0] = dx * inv;
  cd[(size_t)e * 3 + 1] = dy * inv;
  cd[(size_t)e * 3 + 2] = dz * inv;
}

__global__ void x_update_kernel(const float* __restrict__ x,
                                const float* __restrict__ xagg,
                                float* __restrict__ xo, int n3)
{
  const int i = blockIdx.x * 256 + threadIdx.x;
  if (i < n3) xo[i] = x[i] + xagg[i] * 0.01f;   // / NORM_FACTOR
}

extern "C" void kernel_launch(void* const* d_in, const int* in_sizes, int n_in,
                              void* d_out, int out_size, void* d_ws, size_t ws_size,
                              hipStream_t stream)
{
  const float* h_in  = (const float*)d_in[0];
  const float* x_in  = (const float*)d_in[1];
  const float* eattr = (const float*)d_in[2];
  const int*   eidx  = (const int*)d_in[3];
  const int N = in_sizes[0] / HD;
  const int E = in_sizes[2];

  const float* P[25];
  for (int i = 0; i < 25; ++i) P[i] = (const float*)d_in[4 + i];
  // P layout: per GCL l in {0,1}: [10l+0]=ew1 [1]=eb1 [2]=ew2 [3]=eb2 [4]=aw
  //           [5]=ab [6]=nw1 [7]=nb1 [8]=nw2 [9]=nb2 ; P[20..24] = eq_w1..eq_w3

  float* h_out = (float*)d_out;                     // [N,128] current/final h
  float* x_out = (float*)d_out + (size_t)N * HD;    // [N,3]

  float* ws     = (float*)d_ws;
  float* radial = ws;                               // [E]
  float* cd     = ws + E;                           // [E,3]
  float* agg    = ws + (size_t)4 * E;               // [N,128]
  float* xagg   = agg + (size_t)N * HD;             // [N,3]

  hipMemcpyAsync(h_out, h_in, (size_t)N * HD * sizeof(float),
                 hipMemcpyDeviceToDevice, stream);

  const dim3 blk(256);
  coord2diff_kernel<<<(E + 255) / 256, blk, 0, stream>>>(x_in, eidx, E, radial, cd);

  const int egrid = (E + BM - 1) / BM;
  const int ngrid = (N + BM - 1) / BM;

  for (int l = 0; l < 2; ++l) {
    const float* const* G = P + 10 * l;
    hipMemsetAsync(agg, 0, (size_t)N * HD * sizeof(float), stream);
    edge_kernel<0><<<egrid, blk, 0, stream>>>(h_out, radial, eattr, eidx, E,
        G[0], G[1], G[2], G[3], G[4], G[5], nullptr, agg);
    node_kernel<<<ngrid, blk, 0, stream>>>(h_out, agg, N, G[6], G[7], G[8], G[9]);
  }

  hipMemsetAsync(xagg, 0, (size_t)N * 3 * sizeof(float), stream);
  edge_kernel<1><<<egrid, blk, 0, stream>>>(h_out, radial, eattr, eidx, E,
      P[20], P[21], P[22], P[23], P[24], nullptr, cd, xagg);
  x_update_kernel<<<(3 * N + 255) / 256, blk, 0, stream>>>(x_in, xagg, x_out, 3 * N);
}

// Round 2
// 1564.526 us; speedup vs baseline: 2.5813x; 2.5813x over previous
//
#include <hip/hip_runtime.h>
#include <cmath>

typedef short bfv8 __attribute__((ext_vector_type(8)));   // 8 bf16 as raw shorts
typedef float fv4  __attribute__((ext_vector_type(4)));

#define MFMA_B16(a,b,c) __builtin_amdgcn_mfma_f32_16x16x32_bf16((a),(b),(c),0,0,0)

__device__ __forceinline__ float siluf(float x) { return x / (1.0f + expf(-x)); }

// pack split-bf16: low 16 bits = hi-part bf16, high 16 bits = lo-part bf16
__device__ __forceinline__ unsigned packsplit(float v) {
  unsigned uh = __float_as_uint(v) & 0xffff0000u;
  float lof = v - __uint_as_float(uh);
  return (uh >> 16) | (__float_as_uint(lof) & 0xffff0000u);
}

// ---------------------------------------------------------------------------
// Fused edge pipeline (MFMA split-bf16).
// Block: 256 thr = 4 waves; 128 edges/block; wave owns 32 rows x 128 cols.
// MODE 0: GCL edge model -> atomics into agg[N,128]
// MODE 1: Equivariant     -> atomics into x_out[N,3] (coord_diff recomputed)
// ---------------------------------------------------------------------------
template <int MODE>
__global__ __launch_bounds__(256, 3)
void edge_mfma(const unsigned short* __restrict__ hhi,
               const unsigned short* __restrict__ hlo,
               const float* __restrict__ radial,
               const float* __restrict__ eattr,
               const int* __restrict__ eidx, int E,
               const unsigned short* __restrict__ w1h, const unsigned short* __restrict__ w1l,
               const float* __restrict__ W1full, const float* __restrict__ b1,
               const unsigned short* __restrict__ w2h, const unsigned short* __restrict__ w2l,
               const float* __restrict__ b2,
               const float* __restrict__ awv, const float* __restrict__ abv,
               const float* __restrict__ xin,
               float* __restrict__ outbuf)
{
  __shared__ int   sRow[128], sCol[128];
  __shared__ float sRad[128], sEa[128];
  __shared__ __align__(16) unsigned sH[4][2048];   // per-wave 16x128 u32 (hi|lo)

  const int tid = threadIdx.x;
  const int w = tid >> 6, l = tid & 63;
  const int c16 = l & 15, g = l >> 4;
  const int e0 = blockIdx.x * 128;

  if (tid < 128) {
    int e = min(e0 + tid, E - 1);
    sRow[tid] = eidx[e];
    sCol[tid] = eidx[E + e];
    sRad[tid] = radial[e];
    sEa[tid]  = eattr[e];
  }
  __syncthreads();

  const int rw = w * 32;
  int nidA[2], nidB[2];
#pragma unroll
  for (int rt = 0; rt < 2; ++rt) {
    nidA[rt] = sRow[rw + rt * 16 + c16];
    nidB[rt] = sCol[rw + rt * 16 + c16];
  }

  fv4 acc[2][8];
#pragma unroll
  for (int a = 0; a < 2; ++a)
#pragma unroll
    for (int b = 0; b < 8; ++b) acc[a][b] = (fv4)0.0f;

  // ---- GEMM1: [32 x 256] x W1^T (k 0..127 = h[row], 128..255 = h[col]) ----
#pragma unroll 2
  for (int kc = 0; kc < 8; ++kc) {
    bfv8 Ah[2], Al[2];
    const int kh = (kc & 3) * 32 + g * 8;
#pragma unroll
    for (int rt = 0; rt < 2; ++rt) {
      const int nid = (kc < 4) ? nidA[rt] : nidB[rt];
      const size_t off = (size_t)nid * 128 + kh;
      Ah[rt] = *(const bfv8*)(hhi + off);
      Al[rt] = *(const bfv8*)(hlo + off);
    }
#pragma unroll
    for (int jt = 0; jt < 8; ++jt) {
      const size_t bo = ((size_t)(kc * 8 + jt) * 64 + l) * 8;
      bfv8 Bh = *(const bfv8*)(w1h + bo);
      bfv8 Bl = *(const bfv8*)(w1l + bo);
#pragma unroll
      for (int rt = 0; rt < 2; ++rt) {
        acc[rt][jt] = MFMA_B16(Ah[rt], Bh, acc[rt][jt]);
        acc[rt][jt] = MFMA_B16(Al[rt], Bh, acc[rt][jt]);
        acc[rt][jt] = MFMA_B16(Ah[rt], Bl, acc[rt][jt]);
      }
    }
  }

  unsigned* sHW = sH[w];
  const float ab0 = (MODE == 0) ? abv[0] : 0.0f;

#pragma unroll 1
  for (int rt = 0; rt < 2; ++rt) {
    // ---- epilogue1: tail cols (radial, ea) + bias + silu -> sH (swizzled) ----
#pragma unroll
    for (int jt = 0; jt < 8; ++jt) {
      const int col = jt * 16 + c16;
      const float wt0 = W1full[(size_t)col * 258 + 256];
      const float wt1 = W1full[(size_t)col * 258 + 257];
      const float bb  = b1[col];
#pragma unroll
      for (int reg = 0; reg < 4; ++reg) {
        const int rr = 4 * g + reg;                 // row within this 16-row tile
        const int er = rw + rt * 16 + rr;           // block-local edge
        const float v = acc[rt][jt][reg] + sRad[er] * wt0 + sEa[er] * wt1 + bb;
        sHW[rr * 128 + (col ^ ((rr & 7) << 2))] = packsplit(siluf(v));
      }
    }

    // ---- GEMM2: silu(H1)[16x128] x W2^T ----
    fv4 accB[8];
#pragma unroll
    for (int jt = 0; jt < 8; ++jt) accB[jt] = (fv4)0.0f;
    const int sxz = (c16 & 7) << 2;
#pragma unroll 2
    for (int kc2 = 0; kc2 < 4; ++kc2) {
      const int k0 = kc2 * 32 + g * 8;
      const int i1 = c16 * 128 + (k0 ^ sxz);
      const int4 q0 = *((const int4*)(sHW + i1));
      const int4 q1 = *((const int4*)(sHW + (i1 ^ 4)));
      bfv8 Ah2, Al2;
      {
        const int qq[8] = {q0.x, q0.y, q0.z, q0.w, q1.x, q1.y, q1.z, q1.w};
#pragma unroll
        for (int i = 0; i < 8; ++i) {
          Ah2[i] = (short)(((unsigned)qq[i]) & 0xffffu);
          Al2[i] = (short)(((unsigned)qq[i]) >> 16);
        }
      }
#pragma unroll
      for (int jt = 0; jt < 8; ++jt) {
        const size_t bo = ((size_t)(kc2 * 8 + jt) * 64 + l) * 8;
        bfv8 Bh = *(const bfv8*)(w2h + bo);
        bfv8 Bl = *(const bfv8*)(w2l + bo);
        accB[jt] = MFMA_B16(Ah2, Bh, accB[jt]);
        accB[jt] = MFMA_B16(Al2, Bh, accB[jt]);
        accB[jt] = MFMA_B16(Ah2, Bl, accB[jt]);
      }
    }

    // ---- epilogue2 ----
    float p[4] = {0.f, 0.f, 0.f, 0.f};
#pragma unroll
    for (int jt = 0; jt < 8; ++jt) {
      const int col = jt * 16 + c16;
      const float bb = b2[col], aa = awv[col];
#pragma unroll
      for (int reg = 0; reg < 4; ++reg) {
        const float m = siluf(accB[jt][reg] + bb);
        accB[jt][reg] = m;
        p[reg] += m * aa;
      }
    }
#pragma unroll
    for (int msk = 1; msk < 16; msk <<= 1) {
#pragma unroll
      for (int reg = 0; reg < 4; ++reg) p[reg] += __shfl_xor(p[reg], msk, 64);
    }

    if constexpr (MODE == 0) {
#pragma unroll
      for (int reg = 0; reg < 4; ++reg) {
        const int er = rw + rt * 16 + 4 * g + reg;
        const int e = e0 + er;
        if (e < E) {
          const float att = 1.0f / (1.0f + expf(-(p[reg] + ab0)));
          float* dst = outbuf + (size_t)sRow[er] * 128;
#pragma unroll
          for (int jt = 0; jt < 8; ++jt)
            unsafeAtomicAdd(dst + jt * 16 + c16, accB[jt][reg] * att);
        }
      }
    } else {
      if (c16 == 0) {
#pragma unroll
        for (int reg = 0; reg < 4; ++reg) {
          const int er = rw + rt * 16 + 4 * g + reg;
          const int e = e0 + er;
          if (e < E) {
            const float s = p[reg] * 0.01f;          // / NORM_FACTOR
            const int nr = sRow[er], nc = sCol[er];
            const float dx = xin[(size_t)nr * 3 + 0] - xin[(size_t)nc * 3 + 0];
            const float dy = xin[(size_t)nr * 3 + 1] - xin[(size_t)nc * 3 + 1];
            const float dz = xin[(size_t)nr * 3 + 2] - xin[(size_t)nc * 3 + 2];
            const float inv = 1.0f / (sqrtf(dx * dx + dy * dy + dz * dz + 1e-8f) + 1.0f);
            unsafeAtomicAdd(outbuf + (size_t)nr * 3 + 0, dx * inv * s);
            unsafeAtomicAdd(outbuf + (size_t)nr * 3 + 1, dy * inv * s);
            unsafeAtomicAdd(outbuf + (size_t)nr * 3 + 2, dz * inv * s);
          }
        }
      }
    }
  }
}

// ---------------------------------------------------------------------------
// Node model (MFMA): msg = silu([h, agg/100] W1^T + b1) W2^T + b2; h += msg
// ---------------------------------------------------------------------------
__global__ __launch_bounds__(256, 3)
void node_mfma(float* __restrict__ hio,
               const unsigned short* __restrict__ hhi,
               const unsigned short* __restrict__ hlo,
               const float* __restrict__ agg, int N,
               const unsigned short* __restrict__ w1h, const unsigned short* __restrict__ w1l,
               const float* __restrict__ b1,
               const unsigned short* __restrict__ w2h, const unsigned short* __restrict__ w2l,
               const float* __restrict__ b2)
{
  __shared__ __align__(16) unsigned sH[4][2048];

  const int tid = threadIdx.x;
  const int w = tid >> 6, l = tid & 63;
  const int c16 = l & 15, g = l >> 4;
  const int n0 = blockIdx.x * 128;
  const int rw = w * 32;

  int rowA[2];
#pragma unroll
  for (int rt = 0; rt < 2; ++rt) rowA[rt] = min(n0 + rw + rt * 16 + c16, N - 1);

  fv4 acc[2][8];
#pragma unroll
  for (int a = 0; a < 2; ++a)
#pragma unroll
    for (int b = 0; b < 8; ++b) acc[a][b] = (fv4)0.0f;

#pragma unroll 2
  for (int kc = 0; kc < 8; ++kc) {
    bfv8 Ah[2], Al[2];
    if (kc < 4) {
      const int kh = kc * 32 + g * 8;
#pragma unroll
      for (int rt = 0; rt < 2; ++rt) {
        const size_t off = (size_t)rowA[rt] * 128 + kh;
        Ah[rt] = *(const bfv8*)(hhi + off);
        Al[rt] = *(const bfv8*)(hlo + off);
      }
    } else {
      const int kh = (kc - 4) * 32 + g * 8;
#pragma unroll
      for (int rt = 0; rt < 2; ++rt) {
        const float4 v0 = *(const float4*)(agg + (size_t)rowA[rt] * 128 + kh);
        const float4 v1 = *(const float4*)(agg + (size_t)rowA[rt] * 128 + kh + 4);
        const float vv[8] = {v0.x, v0.y, v0.z, v0.w, v1.x, v1.y, v1.z, v1.w};
#pragma unroll
        for (int i = 0; i < 8; ++i) {
          const float xs = vv[i] * 0.01f;            // agg / normalization_factor
          const unsigned uh = __float_as_uint(xs) & 0xffff0000u;
          Ah[rt][i] = (short)(uh >> 16);
          const float lof = xs - __uint_as_float(uh);
          Al[rt][i] = (short)(__float_as_uint(lof) >> 16);
        }
      }
    }
#pragma unroll
    for (int jt = 0; jt < 8; ++jt) {
      const size_t bo = ((size_t)(kc * 8 + jt) * 64 + l) * 8;
      bfv8 Bh = *(const bfv8*)(w1h + bo);
      bfv8 Bl = *(const bfv8*)(w1l + bo);
#pragma unroll
      for (int rt = 0; rt < 2; ++rt) {
        acc[rt][jt] = MFMA_B16(Ah[rt], Bh, acc[rt][jt]);
        acc[rt][jt] = MFMA_B16(Al[rt], Bh, acc[rt][jt]);
        acc[rt][jt] = MFMA_B16(Ah[rt], Bl, acc[rt][jt]);
      }
    }
  }

  unsigned* sHW = sH[w];
#pragma unroll 1
  for (int rt = 0; rt < 2; ++rt) {
#pragma unroll
    for (int jt = 0; jt < 8; ++jt) {
      const int col = jt * 16 + c16;
      const float bb = b1[col];
#pragma unroll
      for (int reg = 0; reg < 4; ++reg) {
        const int rr = 4 * g + reg;
        sHW[rr * 128 + (col ^ ((rr & 7) << 2))] = packsplit(siluf(acc[rt][jt][reg] + bb));
      }
    }

    fv4 accB[8];
#pragma unroll
    for (int jt = 0; jt < 8; ++jt) accB[jt] = (fv4)0.0f;
    const int sxz = (c16 & 7) << 2;
#pragma unroll 2
    for (int kc2 = 0; kc2 < 4; ++kc2) {
      const int k0 = kc2 * 32 + g * 8;
      const int i1 = c16 * 128 + (k0 ^ sxz);
      const int4 q0 = *((const int4*)(sHW + i1));
      const int4 q1 = *((const int4*)(sHW + (i1 ^ 4)));
      bfv8 Ah2, Al2;
      {
        const int qq[8] = {q0.x, q0.y, q0.z, q0.w, q1.x, q1.y, q1.z, q1.w};
#pragma unroll
        for (int i = 0; i < 8; ++i) {
          Ah2[i] = (short)(((unsigned)qq[i]) & 0xffffu);
          Al2[i] = (short)(((unsigned)qq[i]) >> 16);
        }
      }
#pragma unroll
      for (int jt = 0; jt < 8; ++jt) {
        const size_t bo = ((size_t)(kc2 * 8 + jt) * 64 + l) * 8;
        bfv8 Bh = *(const bfv8*)(w2h + bo);
        bfv8 Bl = *(const bfv8*)(w2l + bo);
        accB[jt] = MFMA_B16(Ah2, Bh, accB[jt]);
        accB[jt] = MFMA_B16(Al2, Bh, accB[jt]);
        accB[jt] = MFMA_B16(Ah2, Bl, accB[jt]);
      }
    }

#pragma unroll
    for (int reg = 0; reg < 4; ++reg) {
      const int n = n0 + rw + rt * 16 + 4 * g + reg;
      if (n < N) {
        float* hp = hio + (size_t)n * 128;
#pragma unroll
        for (int jt = 0; jt < 8; ++jt) {
          const int col = jt * 16 + c16;
          hp[col] += accB[jt][reg] + b2[col];        // residual add
        }
      }
    }
  }
}

// radial only (coord_diff recomputed in the equivariant epilogue)
__global__ void radial_kernel(const float* __restrict__ x,
                              const int* __restrict__ eidx, int E,
                              float* __restrict__ radial)
{
  const int e = blockIdx.x * 256 + threadIdx.x;
  if (e >= E) return;
  const int r = eidx[e], c = eidx[E + e];
  const float dx = x[(size_t)r * 3 + 0] - x[(size_t)c * 3 + 0];
  const float dy = x[(size_t)r * 3 + 1] - x[(size_t)c * 3 + 1];
  const float dz = x[(size_t)r * 3 + 2] - x[(size_t)c * 3 + 2];
  radial[e] = dx * dx + dy * dy + dz * dz;
}

// split fp32 -> bf16 hi/lo planes (row-major [N,128])
__global__ void split_kernel(const float* __restrict__ src,
                             unsigned short* __restrict__ hi,
                             unsigned short* __restrict__ lo, int n4)
{
  const int i = blockIdx.x * 256 + threadIdx.x;
  if (i >= n4) return;
  const float4 v = ((const float4*)src)[i];
  const float vv[4] = {v.x, v.y, v.z, v.w};
  ushort4 ho, lq;
  unsigned short* hp = (unsigned short*)&ho;
  unsigned short* lp = (unsigned short*)&lq;
#pragma unroll
  for (int k = 0; k < 4; ++k) {
    const unsigned uh = __float_as_uint(vv[k]) & 0xffff0000u;
    hp[k] = (unsigned short)(uh >> 16);
    const float lof = vv[k] - __uint_as_float(uh);
    lp[k] = (unsigned short)(__float_as_uint(lof) >> 16);
  }
  ((ushort4*)hi)[i] = ho;
  ((ushort4*)lo)[i] = lq;
}

// weight prep: W[j][k] (row-major, stride SW) -> MFMA B-frag layout hi/lo planes
struct WDesc { const float* src; unsigned short* hi; unsigned short* lo; int K; int SW; };
struct WAll { WDesc m[10]; };

__global__ void wprep_kernel(WAll wa)
{
  const WDesc d = wa.m[blockIdx.y];
  const int idx = blockIdx.x * 256 + threadIdx.x;
  const int j = idx & 127, k = idx >> 7;
  if (k >= d.K) return;
  const float v = d.src[(size_t)j * d.SW + k];
  const unsigned uh = __float_as_uint(v) & 0xffff0000u;
  const float lof = v - __uint_as_float(uh);
  // frag index: [ktile][jtile][lane=g*16+c][8]
  const int fo = ((((k >> 5) * 8 + (j >> 4)) * 64) + ((k >> 3) & 3) * 16 + (j & 15)) * 8 + (k & 7);
  d.hi[fo] = (unsigned short)(uh >> 16);
  d.lo[fo] = (unsigned short)(__float_as_uint(lof) >> 16);
}

extern "C" void kernel_launch(void* const* d_in, const int* in_sizes, int n_in,
                              void* d_out, int out_size, void* d_ws, size_t ws_size,
                              hipStream_t stream)
{
  const float* h_in  = (const float*)d_in[0];
  const float* x_in  = (const float*)d_in[1];
  const float* eattr = (const float*)d_in[2];
  const int*   eidx  = (const int*)d_in[3];
  const int N = in_sizes[0] / 128;
  const int E = in_sizes[2];

  const float* P[25];
  for (int i = 0; i < 25; ++i) P[i] = (const float*)d_in[4 + i];

  float* h_out = (float*)d_out;                     // [N,128]
  float* x_out = (float*)d_out + (size_t)N * 128;   // [N,3]

  float* radial = (float*)d_ws;                     // [E]
  float* agg    = radial + E;                       // [N,128]
  unsigned short* hhi = (unsigned short*)(agg + (size_t)N * 128);
  unsigned short* hlo = hhi + (size_t)N * 128;
  unsigned short* wptr = hlo + (size_t)N * 128;

  WAll wa;
  auto addw = [&](int slot, const float* s, int K, int SW) {
    wa.m[slot].src = s; wa.m[slot].hi = wptr; wa.m[slot].lo = wptr + (size_t)K * 128;
    wa.m[slot].K = K; wa.m[slot].SW = SW;
    wptr += (size_t)2 * K * 128;
  };
  addw(0, P[0], 256, 258);  addw(1, P[2], 128, 128);   // g0 ew1, ew2
  addw(2, P[6], 256, 256);  addw(3, P[8], 128, 128);   // g0 nw1, nw2
  addw(4, P[10], 256, 258); addw(5, P[12], 128, 128);  // g1 ew1, ew2
  addw(6, P[16], 256, 256); addw(7, P[18], 128, 128);  // g1 nw1, nw2
  addw(8, P[20], 256, 258); addw(9, P[22], 128, 128);  // eq w1, w2

  hipMemcpyAsync(h_out, h_in, (size_t)N * 128 * sizeof(float),
                 hipMemcpyDeviceToDevice, stream);
  hipMemcpyAsync(x_out, x_in, (size_t)N * 3 * sizeof(float),
                 hipMemcpyDeviceToDevice, stream);

  radial_kernel<<<(E + 255) / 256, 256, 0, stream>>>(x_in, eidx, E, radial);
  wprep_kernel<<<dim3(128, 10), 256, 0, stream>>>(wa);

  const int n4 = N * 32;                 // N*128/4
  const int sg = (n4 + 255) / 256;
  const int eg = (E + 127) / 128;
  const int ng = (N + 127) / 128;

  for (int lyr = 0; lyr < 2; ++lyr) {
    const float* const* G = P + 10 * lyr;
    const WDesc* M = &wa.m[4 * lyr];
    split_kernel<<<sg, 256, 0, stream>>>(h_out, hhi, hlo, n4);
    hipMemsetAsync(agg, 0, (size_t)N * 128 * sizeof(float), stream);
    edge_mfma<0><<<eg, 256, 0, stream>>>(hhi, hlo, radial, eattr, eidx, E,
        M[0].hi, M[0].lo, G[0], G[1], M[1].hi, M[1].lo, G[3],
        G[4], G[5], nullptr, agg);
    node_mfma<<<ng, 256, 0, stream>>>(h_out, hhi, hlo, agg, N,
        M[2].hi, M[2].lo, G[7], M[3].hi, M[3].lo, G[9]);
  }

  split_kernel<<<sg, 256, 0, stream>>>(h_out, hhi, hlo, n4);
  edge_mfma<1><<<eg, 256, 0, stream>>>(hhi, hlo, radial, eattr, eidx, E,
      wa.m[8].hi, wa.m[8].lo, P[20], P[21], wa.m[9].hi, wa.m[9].lo, P[23],
      P[24], nullptr, x_in, x_out);
}